// Round 1
// baseline (7054.180 us; speedup 1.0000x reference)
//
#include <hip/hip_runtime.h>
#include <hip/hip_bf16.h>

#define T_STEPS 512
#define BATCH   256
#define DIN     256
#define DHID    256
#define DCOMB   512
#define NALL    1024     // 4 gates * DHID
#define BBLK    16       // batch rows per workgroup
#define NWG     16       // BATCH / BBLK
#define NTHREADS 512     // 8 waves
#define KT      16       // K tiles of 32 over DCOMB
#define NT_W    8        // n-tiles (of 16) per wave: 64 ntiles / 8 waves

typedef short bf16_t;
typedef __attribute__((ext_vector_type(8))) short short8;
typedef __attribute__((ext_vector_type(4))) float f32x4;

#define APAD 8
#define AROW (DCOMB + APAD)   // 520 bf16 -> 1040 B row stride (16B aligned)
#define THROW (DHID + 1)      // 257 floats, +1 pad to spread banks

// LDS carve (bytes)
#define OFF_A    0
#define SZ_A     (BBLK * AROW * 2)            // 16640
#define OFF_TH   (OFF_A + SZ_A)
#define SZ_TH    (4 * BBLK * THROW * 4)       // 65792
#define OFF_C    (OFF_TH + SZ_TH)
#define SZ_C     (BBLK * DHID * 4)            // 16384
#define OFF_SEG  (OFF_C + SZ_C)
#define SZ_SEG   (64 * 8 * 4)                 // 2048
#define OFF_B    (OFF_SEG + SZ_SEG)
#define SZ_B     (NALL * 4)                   // 4096
#define OFF_TMP  (OFF_B + SZ_B)
#define SZ_TMP   16
#define LDS_TOTAL (OFF_TMP + SZ_TMP)          // 104976

__device__ inline short f2bf(float f) {
  union { float f; unsigned u; } v; v.f = f;
  unsigned r = (v.u + 0x7FFFu + ((v.u >> 16) & 1u)) >> 16;
  return (short)r;
}

__device__ inline float fast_sigmoid(float x) {
  return 1.f / (1.f + __expf(-x));
}

__device__ inline float fast_tanh(float x) {
  float ax = fabsf(x);
  float e = __expf(2.f * ax);             // inf-safe: 1 - 2/inf = 1
  float r = 1.f - 2.f / (e + 1.f);
  return copysignf(r, x);
}

// Pack W into MFMA-B-fragment order: elem[((nt*16+kt)*64+lane)*8 + j] =
// bf16( W[gate][nrow][k] ), n = nt*16+(lane&15), gate=n>>8, nrow=n&255,
// k = kt*32 + (lane>>4)*8 + j.  Also pack bias[1024] and temps[4].
__global__ __launch_bounds__(256) void pack_w(
    const float* __restrict__ Wf, const float* __restrict__ Wi,
    const float* __restrict__ Wg, const float* __restrict__ Wo,
    const float* __restrict__ bf_, const float* __restrict__ bi_,
    const float* __restrict__ bg_, const float* __restrict__ bo_,
    const float* __restrict__ tf_, const float* __restrict__ ti_,
    const float* __restrict__ tg_, const float* __restrict__ to_,
    bf16_t* __restrict__ Wp, float* __restrict__ bias,
    float* __restrict__ temps)
{
  int tid = blockIdx.x * 256 + threadIdx.x;   // 65536 threads
  int lane = tid & 63;
  int kt = (tid >> 6) & 15;
  int nt = tid >> 10;
  int n = nt * 16 + (lane & 15);
  int gate = n >> 8, nrow = n & 255;
  int k = kt * 32 + (lane >> 4) * 8;
  const float* W = gate == 0 ? Wf : gate == 1 ? Wi : gate == 2 ? Wg : Wo;
  const float* src = W + nrow * DCOMB + k;
  short8 d;
#pragma unroll
  for (int j = 0; j < 8; ++j) d[j] = f2bf(src[j]);
  *(short8*)(Wp + (size_t)tid * 8) = d;

  if (tid < NALL) {
    int g2 = tid >> 8;
    const float* bs = g2 == 0 ? bf_ : g2 == 1 ? bi_ : g2 == 2 ? bg_ : bo_;
    bias[tid] = bs[tid & 255];
  }
  if (tid < 4) {
    const float* ts = tid == 0 ? tf_ : tid == 1 ? ti_ : tid == 2 ? tg_ : to_;
    temps[tid] = ts[0];
  }
}

__global__ __launch_bounds__(NTHREADS) void qlstm_rec(
    const float* __restrict__ x,      // [T, B, DIN]
    const bf16_t* __restrict__ Wp,    // packed bf16 W
    const float* __restrict__ bias,   // [1024]
    const float* __restrict__ temps,  // [4]
    float* __restrict__ out)          // [T*B*DHID + 2*B*DHID]
{
  extern __shared__ char smem[];
  bf16_t* A  = (bf16_t*)(smem + OFF_A);   // [BBLK][AROW] comb tile (x|h) bf16
  float* TH  = (float*)(smem + OFF_TH);   // [4][BBLK][THROW] cos(theta) -> act
  float* Cst = (float*)(smem + OFF_C);    // [BBLK][DHID] cell state
  float* seg = (float*)(smem + OFF_SEG);  // [64][8] segment products
  float* Bls = (float*)(smem + OFF_B);    // [1024] bias
  float* Tls = (float*)(smem + OFF_TMP);  // [4] temps

  const int tid  = threadIdx.x;
  const int wave = tid >> 6, lane = tid & 63;
  const int b0   = blockIdx.x * BBLK;

  // init: bias, temps, c=0, h=0
  for (int i = tid; i < NALL; i += NTHREADS) Bls[i] = bias[i];
  if (tid < 4) Tls[tid] = temps[tid];
  for (int i = tid; i < BBLK * DHID; i += NTHREADS) {
    Cst[i] = 0.f;
    A[(i >> 8) * AROW + DIN + (i & 255)] = 0;
  }
  __syncthreads();

  // MFMA A-fragment coordinates: lane holds A[lane&15][(lane>>4)*8 + j]
  const int arow  = lane & 15;
  const int acol0 = (lane >> 4) * 8;
  // W base for this wave (ntiles wave*8 .. wave*8+7)
  const bf16_t* wb = Wp + (size_t)wave * 65536 + lane * 8;

  // cumprod mapping: 8 threads per (gate,b) row
  const int row = tid >> 3;          // 0..63 = gate*16 + b
  const int s   = tid & 7;
  float* rp = TH + row * THROW;
  const int rgate = row >> 4;

  for (int t = 0; t < T_STEPS; ++t) {
    // ---- 1. load x tile -> A[:, 0:256] (bf16) ----
    {
      int r = tid >> 5, c0 = (tid & 31) * 8;
      const float4* xs = (const float4*)(x + ((size_t)t * BATCH + b0 + r) * DIN + c0);
      float4 v0 = xs[0];
      float4 v1 = xs[1];
      short8 d;
      d[0] = f2bf(v0.x); d[1] = f2bf(v0.y); d[2] = f2bf(v0.z); d[3] = f2bf(v0.w);
      d[4] = f2bf(v1.x); d[5] = f2bf(v1.y); d[6] = f2bf(v1.z); d[7] = f2bf(v1.w);
      *(short8*)&A[r * AROW + c0] = d;
    }
    __syncthreads();  // S1

    // ---- 2. GEMM: theta[16,1024] = A[16,512] @ W^T, W streamed from L2 ----
    f32x4 acc[NT_W];
#pragma unroll
    for (int i = 0; i < NT_W; ++i) acc[i] = (f32x4){0.f, 0.f, 0.f, 0.f};
#pragma unroll 2
    for (int kt = 0; kt < KT; ++kt) {
      short8 a = *(const short8*)&A[arow * AROW + kt * 32 + acol0];
#pragma unroll
      for (int i = 0; i < NT_W; ++i) {
        short8 b = *(const short8*)(wb + ((size_t)(i * 16 + kt)) * 512);
        acc[i] = __builtin_amdgcn_mfma_f32_16x16x32_bf16(a, b, acc[i], 0, 0, 0);
      }
    }

    // ---- 3. cos(theta + bias) -> TH (C/D layout: col=lane&15, row=(lane>>4)*4+r) ----
#pragma unroll
    for (int i = 0; i < NT_W; ++i) {
      int n = wave * 128 + i * 16 + (lane & 15);
      int gate = n >> 8, kk = n & 255;
      float bv = Bls[n];
      float* dst = TH + (gate * BBLK) * THROW + kk;
      int brow = (lane >> 4) * 4;
#pragma unroll
      for (int r = 0; r < 4; ++r)
        dst[(brow + r) * THROW] = __cosf(acc[i][r] + bv);
    }
    __syncthreads();  // S2

    // ---- 4a. cumprod pass 1: segment products (order-free, staggered reads) ----
    {
      float p = 1.f;
#pragma unroll
      for (int j = 0; j < 32; ++j) p *= rp[s * 32 + ((j + s * 4) & 31)];
      seg[row * 8 + s] = p;
    }
    __syncthreads();  // S3

    // ---- 4b. cumprod pass 2: prefix, /temp, activation, in place ----
    {
      float pre = 1.f;
      for (int j = 0; j < s; ++j) pre *= seg[row * 8 + j];
      float invt = 1.f / Tls[rgate];
      float run = pre;
#pragma unroll
      for (int j = 0; j < 32; ++j) {
        run *= rp[s * 32 + j];
        float v = run * invt;
        rp[s * 32 + j] = (rgate == 2) ? fast_tanh(v) : fast_sigmoid(v);
      }
    }
    __syncthreads();  // S4

    // ---- 5. cell update: c = f*c + i*g; h = o*tanh(c) ----
#pragma unroll
    for (int j = 0; j < 8; ++j) {
      int idx = tid + NTHREADS * j;     // 0..4095
      int b = idx >> 8, kk = idx & 255;
      float fv = TH[(0 * BBLK + b) * THROW + kk];
      float iv = TH[(1 * BBLK + b) * THROW + kk];
      float gv = TH[(2 * BBLK + b) * THROW + kk];
      float ov = TH[(3 * BBLK + b) * THROW + kk];
      float c  = fv * Cst[b * DHID + kk] + iv * gv;
      Cst[b * DHID + kk] = c;
      float h = ov * fast_tanh(c);
      out[((size_t)t * BATCH + b0 + b) * DHID + kk] = h;
      A[b * AROW + DIN + kk] = f2bf(h);
      if (t == T_STEPS - 1) {
        out[((size_t)T_STEPS * BATCH + b0 + b) * DHID + kk] = h;          // hx
        out[((size_t)T_STEPS * BATCH + BATCH + b0 + b) * DHID + kk] = c;  // cx
      }
    }
    __syncthreads();  // S5
  }
}

extern "C" void kernel_launch(void* const* d_in, const int* in_sizes, int n_in,
                              void* d_out, int out_size, void* d_ws, size_t ws_size,
                              hipStream_t stream) {
  const float* x   = (const float*)d_in[0];
  const float* Wf  = (const float*)d_in[1];
  const float* bf_ = (const float*)d_in[2];
  const float* tf_ = (const float*)d_in[3];
  const float* Wi  = (const float*)d_in[4];
  const float* bi_ = (const float*)d_in[5];
  const float* ti_ = (const float*)d_in[6];
  const float* Wg  = (const float*)d_in[7];
  const float* bg_ = (const float*)d_in[8];
  const float* tg_ = (const float*)d_in[9];
  const float* Wo  = (const float*)d_in[10];
  const float* bo_ = (const float*)d_in[11];
  const float* to_ = (const float*)d_in[12];

  bf16_t* Wp   = (bf16_t*)d_ws;                           // 1 MB packed W
  float* bias  = (float*)((char*)d_ws + (1 << 20));        // 4 KB
  float* temps = (float*)((char*)d_ws + (1 << 20) + 4096); // 16 B

  hipLaunchKernelGGL(pack_w, dim3(256), dim3(256), 0, stream,
                     Wf, Wi, Wg, Wo, bf_, bi_, bg_, bo_, tf_, ti_, tg_, to_,
                     Wp, bias, temps);

  // >64KB dynamic LDS: opt in (no-op if already set; not a stream op)
  (void)hipFuncSetAttribute((const void*)qlstm_rec,
                            hipFuncAttributeMaxDynamicSharedMemorySize,
                            LDS_TOTAL);

  hipLaunchKernelGGL(qlstm_rec, dim3(NWG), dim3(NTHREADS), LDS_TOTAL, stream,
                     x, Wp, bias, temps, (float*)d_out);
}